// Round 10
// baseline (840.684 us; speedup 1.0000x reference)
//
#include <hip/hip_runtime.h>

constexpr int DEG = 32;
constexpr int BTHREADS = 1024;   // 16 waves on one CU; only __syncthreads needed

// ---------------------------------------------------------------------------
// Per-source-node stable sort of the 32 outgoing edges by rotation error.
// Replicates lexsort((err, src)) — src blocks contiguous, stable tie-break.
// ---------------------------------------------------------------------------
__global__ void sort_edges_kernel(const float* __restrict__ eattr,
                                  const int* __restrict__ dst,
                                  int* __restrict__ nbr,
                                  int* __restrict__ eidx,
                                  int E) {
    __shared__ float serr[256];
    int e = blockIdx.x * 256 + threadIdx.x;
    float err = 1e30f;
    if (e < E) {
        float w = fabsf(eattr[e * 4 + 0]);
        w = fminf(w, 1.0f);
        float a = acosf(w);
        err = 2.0f * (a * 57.29577951308232f);
    }
    serr[threadIdx.x] = err;
    __syncthreads();
    if (e < E) {
        int s = e & (DEG - 1);
        int base = (int)threadIdx.x - s;
        int rank = 0;
        for (int t = 0; t < DEG; ++t) {
            float et = serr[base + t];
            rank += (int)((et < err) || (et == err && t < s));
        }
        int u = e >> 5;
        nbr[(u << 5) + rank] = dst[e];
        eidx[(u << 5) + rank] = e;
    }
}

// L1-bypassing read of a claim word: atomics (atomicMin) update L2 only and
// __syncthreads does NOT invalidate L1, so a plain read in the same kernel
// could see a stale line. AGENT-scope relaxed atomic load forces L2.
__device__ __forceinline__ int claim_ld(const int* p) {
    return __hip_atomic_load(p, __ATOMIC_RELAXED, __HIP_MEMORY_SCOPE_AGENT);
}

// ---------------------------------------------------------------------------
// SINGLE-WORKGROUP level-synchronous BFS. Exact sequential semantics via
// claim key (parent_queue_pos<<5)|slot (atomicMin picks the first-touch
// winner in queue-order x slot-order) + in-order append via per-thread
// contiguous chunks and a block scan. No grid syncs, no cooperative launch:
// R6/R9 established each inter-block coordination event costs ~10-30 us on
// 8-XCD gfx950; this kernel has zero of them.
//   - visited: LDS bitmask (2.5 KB) — coherent, zero-latency.
//   - per-level: [claims] bar [wins->wmask, scan] bar [append+quat] bar.
// ---------------------------------------------------------------------------
__global__ void __launch_bounds__(BTHREADS)
bfs_kernel(const float* __restrict__ eattr,
           const int* __restrict__ nbr,
           const int* __restrict__ eidx,
           int* __restrict__ queue,
           int* __restrict__ claim,
           int* __restrict__ wmask,
           float* __restrict__ out,      // [0]=start, [1..]=quat[N][4]
           const int* __restrict__ startp,
           int N) {
    __shared__ unsigned s_visbit[640];          // ceil(20000/32)=625, padded
    __shared__ int s_wsum[BTHREADS / 64];
    __shared__ int s_wbase[BTHREADS / 64];
    __shared__ int s_total;

    const int tid = threadIdx.x;
    float* quat = out + 1;
    const float4* eattr4 = (const float4*)eattr;
    const int start = *startp;
    const int NB = (N + 31) >> 5;

    // init (d_out/d_ws re-poisoned before every launch)
    for (int i = tid; i < NB; i += BTHREADS) s_visbit[i] = 0u;
    for (int v = tid; v < N; v += BTHREADS) {
        claim[v] = 0x7FFFFFFF;
        quat[4 * v + 0] = 1.0f;
        quat[4 * v + 1] = 0.0f;
        quat[4 * v + 2] = 0.0f;
        quat[4 * v + 3] = 0.0f;
    }
    if (tid == 0) {
        queue[0] = start;
        out[0] = (float)start;
    }
    __syncthreads();
    if (tid == 0) atomicOr(&s_visbit[start >> 5], 1u << (start & 31));
    __syncthreads();

    int head = 0, tail = 1;
    while (head < tail) {
        const int F = tail - head;
        const int K = (F + BTHREADS - 1) / BTHREADS;   // nodes per thread (contig)
        const int i0 = min(F, tid * K);
        const int i1 = min(F, i0 + K);

        // ---- Phase A: propose claims (visbit stable; LDS reads are cheap) ----
        for (int i = i0; i < i1; ++i) {
            const int p = head + i;
            const int u = queue[p];
            const int4* row = (const int4*)&nbr[u << 5];
            #pragma unroll
            for (int r = 0; r < 8; ++r) {
                int4 q4 = row[r];
                int vs[4] = {q4.x, q4.y, q4.z, q4.w};
                #pragma unroll
                for (int k = 0; k < 4; ++k) {
                    int v = vs[k];
                    if (!((s_visbit[v >> 5] >> (v & 31)) & 1u))
                        atomicMin(&claim[v], (p << 5) + (4 * r + k));
                }
            }
        }
        __syncthreads();

        // ---- Phase B1: detect wins, store masks, per-thread win count ----
        int tx = 0;
        for (int i = i0; i < i1; ++i) {
            const int p = head + i;
            const int u = queue[p];
            const int4* row = (const int4*)&nbr[u << 5];
            int mask = 0;
            #pragma unroll
            for (int r = 0; r < 8; ++r) {
                int4 q4 = row[r];
                int vs[4] = {q4.x, q4.y, q4.z, q4.w};
                #pragma unroll
                for (int k = 0; k < 4; ++k) {
                    int v = vs[k];
                    int s = 4 * r + k;
                    if (!((s_visbit[v >> 5] >> (v & 31)) & 1u) &&
                        claim_ld(&claim[v]) == ((p << 5) + s))
                        mask |= 1 << s;
                }
            }
            wmask[i] = mask;
            tx += __popc(mask);
        }

        // ---- block exclusive scan over per-thread win counts ----
        {
            int lane = tid & 63, wid = tid >> 6;
            int incl = tx;
            for (int d = 1; d < 64; d <<= 1) {
                int tt = __shfl_up(incl, d, 64);
                if (lane >= d) incl += tt;
            }
            if (lane == 63) s_wsum[wid] = incl;
            __syncthreads();
            if (tid == 0) {
                int acc = 0;
                for (int w = 0; w < BTHREADS / 64; ++w) {
                    s_wbase[w] = acc;
                    acc += s_wsum[w];
                }
                s_total = acc;
            }
            __syncthreads();
            int pos = tail + s_wbase[wid] + (incl - tx);
            const int total = s_total;

            // ---- Phase B2: winners -> quat, visbit, in-order queue append ----
            for (int i = i0; i < i1; ++i) {
                int mask = wmask[i];
                if (!mask) continue;
                const int p = head + i;
                const int u = queue[p];
                float pw = quat[4 * u + 0], px = quat[4 * u + 1];
                float py = quat[4 * u + 2], pz = quat[4 * u + 3];
                while (mask) {
                    int s = __ffs(mask) - 1;
                    mask &= mask - 1;
                    int v = nbr[(u << 5) + s];
                    float4 q = eattr4[eidx[(u << 5) + s]];
                    float qw = q.x, qx = -q.y, qy = -q.z, qz = -q.w;
                    quat[4 * v + 0] = qw * pw - qx * px - qy * py - qz * pz;
                    quat[4 * v + 1] = qw * px + qx * pw + qy * pz - qz * py;
                    quat[4 * v + 2] = qw * py - qx * pz + qy * pw + qz * px;
                    quat[4 * v + 3] = qw * pz + qx * py - qy * px + qz * pw;
                    atomicOr(&s_visbit[v >> 5], 1u << (v & 31));
                    queue[pos++] = v;
                }
            }
            __syncthreads();
            head = tail;
            tail += total;
        }
    }
}

extern "C" void kernel_launch(void* const* d_in, const int* in_sizes, int n_in,
                              void* d_out, int out_size, void* d_ws, size_t ws_size,
                              hipStream_t stream) {
    const float* eattr = (const float*)d_in[0];
    const int* edge_index = (const int*)d_in[1];
    const int* startp = (const int*)d_in[2];
    const int E = in_sizes[0] / 4;   // 640000
    const int N = E / DEG;           // 20000
    const int* dst = edge_index + E; // row 1 of [2, E]

    char* ws = (char*)d_ws;
    int* nbr = (int*)ws;    ws += (size_t)E * 4;
    int* eidx = (int*)ws;   ws += (size_t)E * 4;
    int* queue = (int*)ws;  ws += (size_t)N * 4;
    int* claim = (int*)ws;  ws += (size_t)N * 4;
    int* wmask = (int*)ws;  ws += (size_t)N * 4;

    sort_edges_kernel<<<dim3((E + 255) / 256), dim3(256), 0, stream>>>(
        eattr, dst, nbr, eidx, E);

    float* out = (float*)d_out;
    bfs_kernel<<<dim3(1), dim3(BTHREADS), 0, stream>>>(
        eattr, nbr, eidx, queue, claim, wmask, out, startp, N);
}

// Round 11
// 278.361 us; speedup vs baseline: 3.0201x; 3.0201x over previous
//
#include <hip/hip_runtime.h>

constexpr int DEG = 32;
constexpr int BLOCKS = 64;     // == wave width; co-resident via cooperative launch
constexpr int THREADS = 256;
constexpr int SOLO_MAX = 64;   // frontier sizes handled by block 0 alone

// ---------------------------------------------------------------------------
// Per-source-node stable sort of the 32 outgoing edges by rotation error.
// Also zero-inits the fence-free barrier words (kernel-end implicit flush
// publishes them before bfs_kernel starts on the same stream).
// ---------------------------------------------------------------------------
__global__ void sort_edges_kernel(const float* __restrict__ eattr,
                                  const int* __restrict__ dst,
                                  int* __restrict__ nbr,
                                  int* __restrict__ eidx,
                                  unsigned* __restrict__ bar,
                                  int E) {
    if (blockIdx.x == 0 && threadIdx.x < 2) bar[threadIdx.x] = 0u;
    __shared__ float serr[256];
    int e = blockIdx.x * 256 + threadIdx.x;
    float err = 1e30f;
    if (e < E) {
        float w = fabsf(eattr[e * 4 + 0]);
        w = fminf(w, 1.0f);
        float a = acosf(w);
        err = 2.0f * (a * 57.29577951308232f);
    }
    serr[threadIdx.x] = err;
    __syncthreads();
    if (e < E) {
        int s = e & (DEG - 1);
        int base = (int)threadIdx.x - s;
        int rank = 0;
        for (int t = 0; t < DEG; ++t) {
            float et = serr[base + t];
            rank += (int)((et < err) || (et == err && t < s));
        }
        int u = e >> 5;
        nbr[(u << 5) + rank] = dst[e];
        eidx[(u << 5) + rank] = e;
    }
}

// --- relaxed AGENT-scope (coherent-point, cache-bypassing) accessors --------
__device__ __forceinline__ int ld_ag(const int* p) {
    return __hip_atomic_load(p, __ATOMIC_RELAXED, __HIP_MEMORY_SCOPE_AGENT);
}
__device__ __forceinline__ void st_ag(int* p, int v) {
    __hip_atomic_store(p, v, __ATOMIC_RELAXED, __HIP_MEMORY_SCOPE_AGENT);
}
__device__ __forceinline__ float ldf_ag(const float* p) {
    return __int_as_float(ld_ag((const int*)p));
}
__device__ __forceinline__ void stf_ag(float* p, float v) {
    st_ag((int*)p, __float_as_int(v));
}

// Fence-free grid barrier: __syncthreads drains each wave's vmcnt (stores
// acked at coherent point) BEFORE the arrival add; consumers read shared data
// only via ld_ag/claim reads, so no L2 writeback/invalidate fences are needed.
// Monotonic phase counter -> no reset, no ABA, uniform across blocks.
__device__ __forceinline__ void gsync(unsigned* bar, unsigned& phase) {
    __syncthreads();
    if (threadIdx.x == 0) {
        phase += 1u;
        unsigned target = phase * (unsigned)BLOCKS;
        unsigned old = __hip_atomic_fetch_add(&bar[0], 1u, __ATOMIC_RELAXED,
                                              __HIP_MEMORY_SCOPE_AGENT);
        if (old + 1u == target) {
            __hip_atomic_store(&bar[1], phase, __ATOMIC_RELAXED,
                               __HIP_MEMORY_SCOPE_AGENT);
        } else {
            while (__hip_atomic_load(&bar[1], __ATOMIC_RELAXED,
                                     __HIP_MEMORY_SCOPE_AGENT) < phase)
                __builtin_amdgcn_s_sleep(2);
        }
    }
    __syncthreads();
}

// ---------------------------------------------------------------------------
// Level-synchronous BFS, exact sequential semantics via claim key
// (parent_queue_pos<<5)|slot + in-order append. No visited[] array: keys are
// monotone in queue position, so atomicMin on a finalized node is a no-op and
// the win test (claim==key, key>=head<<5) can't match an earlier level's key.
// claim[start] = -1 sentinel kills self-loop false wins.
// 2 fence-free syncs per grid level; block-0 solo bursts for tiny frontiers.
// ---------------------------------------------------------------------------
__global__ void __launch_bounds__(THREADS)
bfs_kernel(const float* __restrict__ eattr,
           const int* __restrict__ nbr,
           const int* __restrict__ eidx,
           int* __restrict__ queue,
           int* __restrict__ claim,
           unsigned* __restrict__ state,  // exchange slot per block (gen-tagged)
           int* __restrict__ ctrl,        // [1]=head, [2]=tail (solo burst)
           unsigned* __restrict__ bar,    // [0]=arrivals, [1]=published phase
           float* __restrict__ out,       // [0]=start, [1..]=quat[N][4]
           const int* __restrict__ startp,
           int N) {
    const int tid = blockIdx.x * blockDim.x + threadIdx.x;
    const int T = gridDim.x * blockDim.x;
    float* quat = out + 1;
    const float4* eattr4 = (const float4*)eattr;
    const int start = *startp;
    unsigned phase = 0;

    __shared__ int s_wsum[THREADS / 64];
    __shared__ int s_wbase[THREADS / 64];
    __shared__ int s_carry;
    __shared__ int s_excl;
    __shared__ int s_total;

    // init (everything is re-poisoned before every launch)
    for (int v = tid; v < N; v += T) {
        st_ag(&claim[v], (v == start) ? -1 : 0x7FFFFFFF);
        stf_ag(&quat[4 * v + 0], 1.0f);
        stf_ag(&quat[4 * v + 1], 0.0f);
        stf_ag(&quat[4 * v + 2], 0.0f);
        stf_ag(&quat[4 * v + 3], 0.0f);
    }
    if (tid == 0) {
        st_ag(&queue[0], start);
        out[0] = (float)start;   // plain: published by kernel-end flush
    }
    gsync(bar, phase);

    int head = 0, tail = 1;
    unsigned gen = 0;
    while (head < tail) {
        const int F = tail - head;

        if (F <= SOLO_MAX) {
            // ---- solo burst: block 0 chews levels alone (syncthreads only) ----
            if (blockIdx.x == 0) {
                int h = head, t = tail;
                while (h < t && (t - h) <= SOLO_MAX) {
                    const int Fb = t - h;
                    for (int e = threadIdx.x; e < Fb * DEG; e += THREADS) {
                        int p = h + (e >> 5), s = e & 31;
                        int u = ld_ag(&queue[p]);
                        int v = nbr[(u << 5) + s];
                        atomicMin(&claim[v], (p << 5) + s);
                    }
                    __syncthreads();
                    int my_c = 0;
                    if ((int)threadIdx.x < Fb) {
                        int p = h + (int)threadIdx.x, u = ld_ag(&queue[p]);
                        for (int s = 0; s < DEG; ++s) {
                            int v = nbr[(u << 5) + s];
                            if (ld_ag(&claim[v]) == ((p << 5) + s)) my_c++;
                        }
                    }
                    int incl = my_c;
                    for (int d = 1; d < 64; d <<= 1) {
                        int tt = __shfl_up(incl, d, 64);
                        if ((threadIdx.x & 63) >= (unsigned)d) incl += tt;
                    }
                    if (threadIdx.x == 63) s_total = incl;
                    __syncthreads();
                    int total = s_total;
                    if ((int)threadIdx.x < Fb) {
                        int p = h + (int)threadIdx.x, u = ld_ag(&queue[p]);
                        int pos = t + (incl - my_c);
                        float pw = ldf_ag(&quat[4 * u + 0]);
                        float px = ldf_ag(&quat[4 * u + 1]);
                        float py = ldf_ag(&quat[4 * u + 2]);
                        float pz = ldf_ag(&quat[4 * u + 3]);
                        for (int s = 0; s < DEG; ++s) {
                            int v = nbr[(u << 5) + s];
                            if (ld_ag(&claim[v]) == ((p << 5) + s)) {
                                float4 q = eattr4[eidx[(u << 5) + s]];
                                float qw = q.x, qx = -q.y, qy = -q.z, qz = -q.w;
                                stf_ag(&quat[4 * v + 0], qw * pw - qx * px - qy * py - qz * pz);
                                stf_ag(&quat[4 * v + 1], qw * px + qx * pw + qy * pz - qz * py);
                                stf_ag(&quat[4 * v + 2], qw * py - qx * pz + qy * pw + qz * px);
                                stf_ag(&quat[4 * v + 3], qw * pz + qx * py - qy * px + qz * pw);
                                st_ag(&queue[pos++], v);
                            }
                        }
                    }
                    __syncthreads();
                    h = t;
                    t += total;
                }
                if (threadIdx.x == 0) { st_ag(&ctrl[1], h); st_ag(&ctrl[2], t); }
            }
            gsync(bar, phase);
            head = ld_ag(&ctrl[1]);
            tail = ld_ag(&ctrl[2]);
        } else {
            // ---- grid level, 2 fence-free syncs ----
            // pass 1: claims, x4 MLP, unconditional atomicMin (no visited)
            {
                const int EDG = F * DEG;
                for (int e = tid; e < EDG; e += 4 * T) {
                    int ee[4]; bool ok[4]; int u[4], v[4];
                    #pragma unroll
                    for (int k = 0; k < 4; ++k) {
                        ee[k] = e + k * T;
                        ok[k] = ee[k] < EDG;
                        u[k] = ok[k] ? ld_ag(&queue[head + (ee[k] >> 5)]) : 0;
                    }
                    #pragma unroll
                    for (int k = 0; k < 4; ++k)
                        v[k] = ok[k] ? nbr[(u[k] << 5) + (ee[k] & 31)] : 0;
                    #pragma unroll
                    for (int k = 0; k < 4; ++k)
                        if (ok[k])
                            atomicMin(&claim[v[k]],
                                      ((head + (ee[k] >> 5)) << 5) + (ee[k] & 31));
                }
            }
            gsync(bar, phase);

            // pass 2: wins (batched claim reads) + block scan + exchange + append
            gen++;
            const int CH = (F + BLOCKS - 1) / BLOCKS;
            const int c0 = blockIdx.x * CH;
            const int c1 = min(F, c0 + CH);
            if (threadIdx.x == 0) s_carry = 0;
            __syncthreads();

            int ms[2] = {0, 0}, ofs[2] = {0, 0};
            #pragma unroll
            for (int st = 0; st < 2; ++st) {
                int i = c0 + st * THREADS + (int)threadIdx.x;
                int x = 0, mask = 0;
                if (i < c1) {
                    int p = head + i, u = ld_ag(&queue[p]);
                    const int4* row = (const int4*)&nbr[u << 5];
                    int vv[32];
                    #pragma unroll
                    for (int r = 0; r < 8; ++r) {
                        int4 q4 = row[r];
                        vv[4 * r + 0] = q4.x; vv[4 * r + 1] = q4.y;
                        vv[4 * r + 2] = q4.z; vv[4 * r + 3] = q4.w;
                    }
                    int cl[32];
                    #pragma unroll
                    for (int s = 0; s < 32; ++s) cl[s] = ld_ag(&claim[vv[s]]);
                    #pragma unroll
                    for (int s = 0; s < 32; ++s)
                        if (cl[s] == ((p << 5) + s)) { mask |= 1 << s; x++; }
                }
                int lane = threadIdx.x & 63, wid = threadIdx.x >> 6;
                int incl = x;
                for (int d = 1; d < 64; d <<= 1) {
                    int tt = __shfl_up(incl, d, 64);
                    if (lane >= d) incl += tt;
                }
                if (lane == 63) s_wsum[wid] = incl;
                __syncthreads();
                if (threadIdx.x == 0) {
                    int acc = s_carry;
                    for (int w = 0; w < THREADS / 64; ++w) {
                        s_wbase[w] = acc;
                        acc += s_wsum[w];
                    }
                    s_carry = acc;
                }
                __syncthreads();
                ms[st] = mask;
                ofs[st] = s_wbase[wid] + incl - x;
                __syncthreads();
            }
            const int agg = s_carry;

            // wave-parallel all-to-all exchange, relaxed + generation tag
            if (threadIdx.x == 0)
                __hip_atomic_store(&state[blockIdx.x],
                                   ((gen & 0xFFu) << 24) | (unsigned)agg,
                                   __ATOMIC_RELAXED, __HIP_MEMORY_SCOPE_AGENT);
            if (threadIdx.x < 64) {
                unsigned sv;
                do {
                    sv = __hip_atomic_load(&state[threadIdx.x], __ATOMIC_RELAXED,
                                           __HIP_MEMORY_SCOPE_AGENT);
                } while ((sv >> 24) != (gen & 0xFFu));
                int a = (int)(sv & 0xFFFFFFu);
                int incl = a;
                for (int d = 1; d < 64; d <<= 1) {
                    int tt = __shfl_up(incl, d, 64);
                    if ((int)(threadIdx.x & 63) >= d) incl += tt;
                }
                int myincl = __shfl(incl, (int)blockIdx.x, 64);
                int mya = __shfl(a, (int)blockIdx.x, 64);
                int tot = __shfl(incl, 63, 64);
                if (threadIdx.x == 0) { s_excl = myincl - mya; s_total = tot; }
            }
            __syncthreads();
            const int excl = s_excl;
            const int total = s_total;

            // append: winners write quat (coherent), queue in sequential order
            #pragma unroll
            for (int st = 0; st < 2; ++st) {
                int i = c0 + st * THREADS + (int)threadIdx.x;
                int mask = ms[st];
                if (i < c1 && mask) {
                    int p = head + i, u = ld_ag(&queue[p]);
                    int pos = tail + excl + ofs[st];
                    float pw = ldf_ag(&quat[4 * u + 0]);
                    float px = ldf_ag(&quat[4 * u + 1]);
                    float py = ldf_ag(&quat[4 * u + 2]);
                    float pz = ldf_ag(&quat[4 * u + 3]);
                    while (mask) {
                        int s = __ffs(mask) - 1;
                        mask &= mask - 1;
                        int v = nbr[(u << 5) + s];
                        float4 q = eattr4[eidx[(u << 5) + s]];
                        float qw = q.x, qx = -q.y, qy = -q.z, qz = -q.w;
                        stf_ag(&quat[4 * v + 0], qw * pw - qx * px - qy * py - qz * pz);
                        stf_ag(&quat[4 * v + 1], qw * px + qx * pw + qy * pz - qz * py);
                        stf_ag(&quat[4 * v + 2], qw * py - qx * pz + qy * pw + qz * px);
                        stf_ag(&quat[4 * v + 3], qw * pz + qx * py - qy * px + qz * pw);
                        st_ag(&queue[pos++], v);
                    }
                }
            }
            gsync(bar, phase);
            head = tail;
            tail += total;
        }
    }
}

extern "C" void kernel_launch(void* const* d_in, const int* in_sizes, int n_in,
                              void* d_out, int out_size, void* d_ws, size_t ws_size,
                              hipStream_t stream) {
    const float* eattr = (const float*)d_in[0];
    const int* edge_index = (const int*)d_in[1];
    const int* startp = (const int*)d_in[2];
    const int E = in_sizes[0] / 4;   // 640000
    const int N = E / DEG;           // 20000
    const int* dst = edge_index + E; // row 1 of [2, E]

    char* ws = (char*)d_ws;
    int* nbr = (int*)ws;            ws += (size_t)E * 4;
    int* eidx = (int*)ws;           ws += (size_t)E * 4;
    int* queue = (int*)ws;          ws += (size_t)N * 4;
    int* claim = (int*)ws;          ws += (size_t)N * 4;
    unsigned int* state = (unsigned int*)ws; ws += (size_t)BLOCKS * 4;
    int* ctrl = (int*)ws;           ws += 64;
    unsigned int* bar = (unsigned int*)ws; ws += 64;

    sort_edges_kernel<<<dim3((E + 255) / 256), dim3(256), 0, stream>>>(
        eattr, dst, nbr, eidx, bar, E);

    float* out = (float*)d_out;
    void* args[] = {(void*)&eattr, (void*)&nbr,   (void*)&eidx, (void*)&queue,
                    (void*)&claim, (void*)&state, (void*)&ctrl, (void*)&bar,
                    (void*)&out,   (void*)&startp, (void*)&N};
    (void)hipLaunchCooperativeKernel((void*)bfs_kernel, dim3(BLOCKS),
                                     dim3(THREADS), args, 0, stream);
}

// Round 12
// 262.713 us; speedup vs baseline: 3.2000x; 1.0596x over previous
//
#include <hip/hip_runtime.h>

typedef unsigned long long ull;

constexpr int DEG = 32;
constexpr int BLOCKS = 64;     // == wave width; co-resident via cooperative launch
constexpr int THREADS = 256;
constexpr int SOLO_MAX = 64;   // frontier sizes handled by block 0 alone

// ---------------------------------------------------------------------------
// Per-source-node stable sort of the 32 outgoing edges by rotation error.
// Also zero-inits the fence-free barrier slots (kernel-end flush publishes).
// ---------------------------------------------------------------------------
__global__ void sort_edges_kernel(const float* __restrict__ eattr,
                                  const int* __restrict__ dst,
                                  int* __restrict__ nbr,
                                  int* __restrict__ eidx,
                                  unsigned* __restrict__ slot,
                                  int E) {
    if (blockIdx.x == 0 && threadIdx.x < 64) slot[threadIdx.x] = 0u;
    __shared__ float serr[256];
    int e = blockIdx.x * 256 + threadIdx.x;
    float err = 1e30f;
    if (e < E) {
        float w = fabsf(eattr[e * 4 + 0]);
        w = fminf(w, 1.0f);
        float a = acosf(w);
        err = 2.0f * (a * 57.29577951308232f);
    }
    serr[threadIdx.x] = err;
    __syncthreads();
    if (e < E) {
        int s = e & (DEG - 1);
        int base = (int)threadIdx.x - s;
        int rank = 0;
        for (int t = 0; t < DEG; ++t) {
            float et = serr[base + t];
            rank += (int)((et < err) || (et == err && t < s));
        }
        int u = e >> 5;
        nbr[(u << 5) + rank] = dst[e];
        eidx[(u << 5) + rank] = e;
    }
}

// --- relaxed AGENT-scope (coherent-point) accessors -------------------------
__device__ __forceinline__ int ld_ag(const int* p) {
    return __hip_atomic_load(p, __ATOMIC_RELAXED, __HIP_MEMORY_SCOPE_AGENT);
}
__device__ __forceinline__ void st_ag(int* p, int v) {
    __hip_atomic_store(p, v, __ATOMIC_RELAXED, __HIP_MEMORY_SCOPE_AGENT);
}
__device__ __forceinline__ ull ld8(const ull* p) {
    return __hip_atomic_load(p, __ATOMIC_RELAXED, __HIP_MEMORY_SCOPE_AGENT);
}
__device__ __forceinline__ void st8(ull* p, ull v) {
    __hip_atomic_store(p, v, __ATOMIC_RELAXED, __HIP_MEMORY_SCOPE_AGENT);
}

// Fence-free grid barrier: per-block slot store + 64-lane all-slot poll.
// __syncthreads before the post drains vmcnt -> all the block's coherent
// stores/atomics are acked at the coherent point before the flag appears.
// Monotonic phase -> no reset / ABA.
__device__ __forceinline__ void gsync(unsigned* slot, unsigned& phase) {
    __syncthreads();
    ++phase;
    if (threadIdx.x == 0)
        __hip_atomic_store(&slot[blockIdx.x], phase, __ATOMIC_RELAXED,
                           __HIP_MEMORY_SCOPE_AGENT);
    if (threadIdx.x < 64) {
        while (__hip_atomic_load(&slot[threadIdx.x], __ATOMIC_RELAXED,
                                 __HIP_MEMORY_SCOPE_AGENT) < phase)
            __builtin_amdgcn_s_sleep(1);
    }
    __syncthreads();
}

// ---------------------------------------------------------------------------
// Level-synchronous BFS, exact sequential semantics via claim key
// (parent_queue_pos<<5)|slot + in-order append.
// Queue records carry the parent quaternion: qrec[p] = {v,qw}{qx,qy}{qz,-}
// (3 x 8B coherent words). quat[] is then WRITE-ONLY plain cached stores
// (published by kernel-end flush); a cleanup pass writes identity for
// unreached nodes + start (disjoint-byte writes only -> XCD-safe).
// No visited[]: keys are monotone in queue position (claim-filter restores
// the cheap skip of finalized nodes without extra state).
// ---------------------------------------------------------------------------
__global__ void __launch_bounds__(THREADS)
bfs_kernel(const float* __restrict__ eattr,
           const int* __restrict__ nbr,
           const int* __restrict__ eidx,
           ull* __restrict__ qrec,        // [N][4] packed queue records
           int* __restrict__ claim,
           unsigned* __restrict__ state,  // exchange slot per block (gen-tagged)
           int* __restrict__ ctrl,        // [1]=head, [2]=tail (solo burst)
           unsigned* __restrict__ slot,   // barrier slots, one per block
           float* __restrict__ out,       // [0]=start, [1..]=quat[N][4]
           const int* __restrict__ startp,
           int N) {
    const int tid = blockIdx.x * blockDim.x + threadIdx.x;
    const int T = gridDim.x * blockDim.x;
    float* quat = out + 1;
    const float4* eattr4 = (const float4*)eattr;
    const int start = *startp;
    unsigned phase = 0;

    __shared__ int s_wsum[THREADS / 64];
    __shared__ int s_wbase[THREADS / 64];
    __shared__ int s_carry;
    __shared__ int s_excl;
    __shared__ int s_total;

    // init: claim sentinel pairs (8B packed), start record. No quat init.
    for (int i = tid; i < (N >> 1); i += T) {
        int v0 = 2 * i, v1 = 2 * i + 1;
        unsigned lo = (v0 == start) ? 0xFFFFFFFFu : 0x7FFFFFFFu;
        unsigned hi = (v1 == start) ? 0xFFFFFFFFu : 0x7FFFFFFFu;
        st8(&((ull*)claim)[i], (ull)lo | ((ull)hi << 32));
    }
    if ((N & 1) && tid == 0)
        st_ag(&claim[N - 1], (N - 1 == start) ? -1 : 0x7FFFFFFF);
    if (tid == 0) {
        st8(&qrec[0], (ull)(unsigned)start | ((ull)0x3F800000u << 32)); // w=1.0
        st8(&qrec[1], 0ull);
        st8(&qrec[2], 0ull);
        out[0] = (float)start;   // plain: published by kernel-end flush
    }
    gsync(slot, phase);

    int head = 0, tail = 1;
    unsigned gen = 0;
    while (head < tail) {
        const int F = tail - head;

        if (F <= SOLO_MAX) {
            // ---- solo burst: block 0 chews levels alone (syncthreads only) ----
            if (blockIdx.x == 0) {
                int h = head, t = tail;
                while (h < t && (t - h) <= SOLO_MAX) {
                    const int Fb = t - h;
                    for (int e = threadIdx.x; e < Fb * DEG; e += THREADS) {
                        int p = h + (e >> 5), s = e & 31;
                        int u = (int)(unsigned)ld8(&qrec[4 * p]);
                        int v = nbr[(u << 5) + s];
                        int key = (p << 5) + s;
                        if (ld_ag(&claim[v]) > key) atomicMin(&claim[v], key);
                    }
                    __syncthreads();
                    int my_c = 0;
                    if ((int)threadIdx.x < Fb) {
                        int p = h + (int)threadIdx.x;
                        int u = (int)(unsigned)ld8(&qrec[4 * p]);
                        for (int s = 0; s < DEG; ++s)
                            if (ld_ag(&claim[nbr[(u << 5) + s]]) == ((p << 5) + s))
                                my_c++;
                    }
                    int incl = my_c;
                    for (int d = 1; d < 64; d <<= 1) {
                        int tt = __shfl_up(incl, d, 64);
                        if ((threadIdx.x & 63) >= (unsigned)d) incl += tt;
                    }
                    if (threadIdx.x == 63) s_total = incl;
                    __syncthreads();
                    int total = s_total;
                    if ((int)threadIdx.x < Fb) {
                        int p = h + (int)threadIdx.x;
                        ull r0 = ld8(&qrec[4 * p]);
                        ull r1 = ld8(&qrec[4 * p + 1]);
                        ull r2 = ld8(&qrec[4 * p + 2]);
                        int u = (int)(unsigned)r0;
                        float pw = __uint_as_float((unsigned)(r0 >> 32));
                        float px = __uint_as_float((unsigned)r1);
                        float py = __uint_as_float((unsigned)(r1 >> 32));
                        float pz = __uint_as_float((unsigned)r2);
                        int pos = t + (incl - my_c);
                        for (int s = 0; s < DEG; ++s) {
                            int v = nbr[(u << 5) + s];
                            if (ld_ag(&claim[v]) == ((p << 5) + s)) {
                                float4 q = eattr4[eidx[(u << 5) + s]];
                                float qw = q.x, qx = -q.y, qy = -q.z, qz = -q.w;
                                float nw = qw * pw - qx * px - qy * py - qz * pz;
                                float nx = qw * px + qx * pw + qy * pz - qz * py;
                                float ny = qw * py - qx * pz + qy * pw + qz * px;
                                float nz = qw * pz + qx * py - qy * px + qz * pw;
                                quat[4 * v + 0] = nw;  // plain cached
                                quat[4 * v + 1] = nx;
                                quat[4 * v + 2] = ny;
                                quat[4 * v + 3] = nz;
                                st8(&qrec[4 * pos],
                                    (ull)(unsigned)v | ((ull)__float_as_uint(nw) << 32));
                                st8(&qrec[4 * pos + 1],
                                    (ull)__float_as_uint(nx) | ((ull)__float_as_uint(ny) << 32));
                                st8(&qrec[4 * pos + 2], (ull)__float_as_uint(nz));
                                pos++;
                            }
                        }
                    }
                    __syncthreads();
                    h = t;
                    t += total;
                }
                if (threadIdx.x == 0) { st_ag(&ctrl[1], h); st_ag(&ctrl[2], t); }
            }
            gsync(slot, phase);
            head = ld_ag(&ctrl[1]);
            tail = ld_ag(&ctrl[2]);
        } else {
            // ---- grid level, 2 fence-free syncs ----
            // Region A: claims, x4 MLP, claim-filtered atomicMin
            {
                const int EDG = F * DEG;
                for (int e = tid; e < EDG; e += 4 * T) {
                    int ee[4]; bool ok[4]; int u[4], v[4], key[4], cl[4];
                    #pragma unroll
                    for (int k = 0; k < 4; ++k) {
                        ee[k] = e + k * T;
                        ok[k] = ee[k] < EDG;
                        int p = head + (ee[k] >> 5);
                        key[k] = (p << 5) + (ee[k] & 31);
                        u[k] = ok[k] ? (int)(unsigned)ld8(&qrec[4 * p]) : 0;
                    }
                    #pragma unroll
                    for (int k = 0; k < 4; ++k)
                        v[k] = ok[k] ? nbr[(u[k] << 5) + (ee[k] & 31)] : 0;
                    #pragma unroll
                    for (int k = 0; k < 4; ++k)
                        cl[k] = ok[k] ? ld_ag(&claim[v[k]]) : -1;
                    #pragma unroll
                    for (int k = 0; k < 4; ++k)
                        if (ok[k] && cl[k] > key[k]) atomicMin(&claim[v[k]], key[k]);
                }
            }
            gsync(slot, phase);

            // Region B: wins + block scan + exchange + append
            gen++;
            const int CH = (F + BLOCKS - 1) / BLOCKS;
            const int c0 = blockIdx.x * CH;
            const int c1 = min(F, c0 + CH);
            if (threadIdx.x == 0) s_carry = 0;
            __syncthreads();

            int ms[2] = {0, 0}, ofs[2] = {0, 0};
            #pragma unroll
            for (int st = 0; st < 2; ++st) {
                int i = c0 + st * THREADS + (int)threadIdx.x;
                int x = 0, mask = 0;
                if (i < c1) {
                    int p = head + i;
                    int u = (int)(unsigned)ld8(&qrec[4 * p]);
                    const int4* row = (const int4*)&nbr[u << 5];
                    int vv[32];
                    #pragma unroll
                    for (int r = 0; r < 8; ++r) {
                        int4 q4 = row[r];
                        vv[4 * r + 0] = q4.x; vv[4 * r + 1] = q4.y;
                        vv[4 * r + 2] = q4.z; vv[4 * r + 3] = q4.w;
                    }
                    int cl[32];
                    #pragma unroll
                    for (int s = 0; s < 32; ++s) cl[s] = ld_ag(&claim[vv[s]]);
                    #pragma unroll
                    for (int s = 0; s < 32; ++s)
                        if (cl[s] == ((p << 5) + s)) { mask |= 1 << s; x++; }
                }
                int lane = threadIdx.x & 63, wid = threadIdx.x >> 6;
                int incl = x;
                for (int d = 1; d < 64; d <<= 1) {
                    int tt = __shfl_up(incl, d, 64);
                    if (lane >= d) incl += tt;
                }
                if (lane == 63) s_wsum[wid] = incl;
                __syncthreads();
                if (threadIdx.x == 0) {
                    int acc = s_carry;
                    for (int w = 0; w < THREADS / 64; ++w) {
                        s_wbase[w] = acc;
                        acc += s_wsum[w];
                    }
                    s_carry = acc;
                }
                __syncthreads();
                ms[st] = mask;
                ofs[st] = s_wbase[wid] + incl - x;
                __syncthreads();
            }
            const int agg = s_carry;

            // wave-parallel all-to-all exchange, relaxed + generation tag
            if (threadIdx.x == 0)
                __hip_atomic_store(&state[blockIdx.x],
                                   ((gen & 0xFFu) << 24) | (unsigned)agg,
                                   __ATOMIC_RELAXED, __HIP_MEMORY_SCOPE_AGENT);
            if (threadIdx.x < 64) {
                unsigned sv;
                do {
                    sv = __hip_atomic_load(&state[threadIdx.x], __ATOMIC_RELAXED,
                                           __HIP_MEMORY_SCOPE_AGENT);
                } while ((sv >> 24) != (gen & 0xFFu));
                int a = (int)(sv & 0xFFFFFFu);
                int incl = a;
                for (int d = 1; d < 64; d <<= 1) {
                    int tt = __shfl_up(incl, d, 64);
                    if ((int)(threadIdx.x & 63) >= d) incl += tt;
                }
                int myincl = __shfl(incl, (int)blockIdx.x, 64);
                int mya = __shfl(a, (int)blockIdx.x, 64);
                int tot = __shfl(incl, 63, 64);
                if (threadIdx.x == 0) { s_excl = myincl - mya; s_total = tot; }
            }
            __syncthreads();
            const int excl = s_excl;
            const int total = s_total;

            // append: winners write quat (plain) + queue record (coherent)
            #pragma unroll
            for (int st = 0; st < 2; ++st) {
                int i = c0 + st * THREADS + (int)threadIdx.x;
                int mask = ms[st];
                if (i < c1 && mask) {
                    int p = head + i;
                    ull r0 = ld8(&qrec[4 * p]);
                    ull r1 = ld8(&qrec[4 * p + 1]);
                    ull r2 = ld8(&qrec[4 * p + 2]);
                    int u = (int)(unsigned)r0;
                    float pw = __uint_as_float((unsigned)(r0 >> 32));
                    float px = __uint_as_float((unsigned)r1);
                    float py = __uint_as_float((unsigned)(r1 >> 32));
                    float pz = __uint_as_float((unsigned)r2);
                    int pos = tail + excl + ofs[st];
                    while (mask) {
                        int s = __ffs(mask) - 1;
                        mask &= mask - 1;
                        int v = nbr[(u << 5) + s];
                        float4 q = eattr4[eidx[(u << 5) + s]];
                        float qw = q.x, qx = -q.y, qy = -q.z, qz = -q.w;
                        float nw = qw * pw - qx * px - qy * py - qz * pz;
                        float nx = qw * px + qx * pw + qy * pz - qz * py;
                        float ny = qw * py - qx * pz + qy * pw + qz * px;
                        float nz = qw * pz + qx * py - qy * px + qz * pw;
                        quat[4 * v + 0] = nw;  // plain cached, write-only
                        quat[4 * v + 1] = nx;
                        quat[4 * v + 2] = ny;
                        quat[4 * v + 3] = nz;
                        st8(&qrec[4 * pos],
                            (ull)(unsigned)v | ((ull)__float_as_uint(nw) << 32));
                        st8(&qrec[4 * pos + 1],
                            (ull)__float_as_uint(nx) | ((ull)__float_as_uint(ny) << 32));
                        st8(&qrec[4 * pos + 2], (ull)__float_as_uint(nz));
                        pos++;
                    }
                }
            }
            gsync(slot, phase);
            head = tail;
            tail += total;
        }
    }

    // cleanup: identity for unreached nodes and the start node (sole writers)
    for (int v = tid; v < N; v += T) {
        int c = ld_ag(&claim[v]);
        if (c == 0x7FFFFFFF || c == -1) {
            quat[4 * v + 0] = 1.0f;
            quat[4 * v + 1] = 0.0f;
            quat[4 * v + 2] = 0.0f;
            quat[4 * v + 3] = 0.0f;
        }
    }
}

extern "C" void kernel_launch(void* const* d_in, const int* in_sizes, int n_in,
                              void* d_out, int out_size, void* d_ws, size_t ws_size,
                              hipStream_t stream) {
    const float* eattr = (const float*)d_in[0];
    const int* edge_index = (const int*)d_in[1];
    const int* startp = (const int*)d_in[2];
    const int E = in_sizes[0] / 4;   // 640000
    const int N = E / DEG;           // 20000
    const int* dst = edge_index + E; // row 1 of [2, E]

    char* ws = (char*)d_ws;
    int* nbr = (int*)ws;            ws += (size_t)E * 4;
    int* eidx = (int*)ws;           ws += (size_t)E * 4;
    ull* qrec = (ull*)ws;           ws += (size_t)N * 32;
    int* claim = (int*)ws;          ws += (size_t)N * 4;
    unsigned int* state = (unsigned int*)ws; ws += (size_t)BLOCKS * 4;
    int* ctrl = (int*)ws;           ws += 64;
    unsigned int* slot = (unsigned int*)ws; ws += 256;

    sort_edges_kernel<<<dim3((E + 255) / 256), dim3(256), 0, stream>>>(
        eattr, dst, nbr, eidx, slot, E);

    float* out = (float*)d_out;
    void* args[] = {(void*)&eattr, (void*)&nbr,   (void*)&eidx, (void*)&qrec,
                    (void*)&claim, (void*)&state, (void*)&ctrl, (void*)&slot,
                    (void*)&out,   (void*)&startp, (void*)&N};
    (void)hipLaunchCooperativeKernel((void*)bfs_kernel, dim3(BLOCKS),
                                     dim3(THREADS), args, 0, stream);
}

// Round 13
// 231.855 us; speedup vs baseline: 3.6259x; 1.1331x over previous
//
#include <hip/hip_runtime.h>

typedef unsigned long long ull;

constexpr int DEG = 32;
constexpr int BLOCKS = 64;     // <= CU count: all-resident under plain dispatch
constexpr int THREADS = 256;
constexpr int SOLO_MAX = 64;   // frontier sizes handled by block 0 alone

// ---------------------------------------------------------------------------
// Per-source-node stable sort of the 32 outgoing edges by rotation error.
// Also zero-inits the fence-free barrier slots (kernel-end flush publishes).
// Kept as a SEPARATE kernel: its kernel-boundary writeback/invalidate is what
// publishes nbr/eidx/slot to all XCDs for the plain cached reads in bfs.
// ---------------------------------------------------------------------------
__global__ void sort_edges_kernel(const float* __restrict__ eattr,
                                  const int* __restrict__ dst,
                                  int* __restrict__ nbr,
                                  int* __restrict__ eidx,
                                  unsigned* __restrict__ slot,
                                  int E) {
    if (blockIdx.x == 0 && threadIdx.x < 64) slot[threadIdx.x] = 0u;
    __shared__ float serr[256];
    int e = blockIdx.x * 256 + threadIdx.x;
    float err = 1e30f;
    if (e < E) {
        float w = fabsf(eattr[e * 4 + 0]);
        w = fminf(w, 1.0f);
        float a = acosf(w);
        err = 2.0f * (a * 57.29577951308232f);
    }
    serr[threadIdx.x] = err;
    __syncthreads();
    if (e < E) {
        int s = e & (DEG - 1);
        int base = (int)threadIdx.x - s;
        int rank = 0;
        for (int t = 0; t < DEG; ++t) {
            float et = serr[base + t];
            rank += (int)((et < err) || (et == err && t < s));
        }
        int u = e >> 5;
        nbr[(u << 5) + rank] = dst[e];
        eidx[(u << 5) + rank] = e;
    }
}

// --- relaxed AGENT-scope (coherent-point) accessors -------------------------
__device__ __forceinline__ int ld_ag(const int* p) {
    return __hip_atomic_load(p, __ATOMIC_RELAXED, __HIP_MEMORY_SCOPE_AGENT);
}
__device__ __forceinline__ void st_ag(int* p, int v) {
    __hip_atomic_store(p, v, __ATOMIC_RELAXED, __HIP_MEMORY_SCOPE_AGENT);
}
__device__ __forceinline__ ull ld8(const ull* p) {
    return __hip_atomic_load(p, __ATOMIC_RELAXED, __HIP_MEMORY_SCOPE_AGENT);
}
__device__ __forceinline__ void st8(ull* p, ull v) {
    __hip_atomic_store(p, v, __ATOMIC_RELAXED, __HIP_MEMORY_SCOPE_AGENT);
}

// Fence-free grid barrier: per-block slot store + 64-lane all-slot poll.
// __syncthreads before the post drains vmcnt -> all the block's coherent
// stores/atomics are acked at the coherent point before the flag appears.
// Monotonic phase -> no reset / ABA. Requires co-residency only (64 blocks
// on 256 CUs under plain dispatch -> guaranteed in practice).
__device__ __forceinline__ void gsync(unsigned* slot, unsigned& phase) {
    __syncthreads();
    ++phase;
    if (threadIdx.x == 0)
        __hip_atomic_store(&slot[blockIdx.x], phase, __ATOMIC_RELAXED,
                           __HIP_MEMORY_SCOPE_AGENT);
    if (threadIdx.x < 64) {
        while (__hip_atomic_load(&slot[threadIdx.x], __ATOMIC_RELAXED,
                                 __HIP_MEMORY_SCOPE_AGENT) < phase)
            __builtin_amdgcn_s_sleep(1);
    }
    __syncthreads();
}

// ---------------------------------------------------------------------------
// Level-synchronous BFS, exact sequential semantics via claim key
// (parent_queue_pos<<5)|slot + in-order append. PLAIN launch (no cooperative
// kernel): R10-vs-R12 timing gap showed hipLaunchCooperativeKernel costs
// ~40+ us in the captured graph; the fence-free barrier never needed it.
// Queue records carry the parent quaternion (3 x 8B coherent words); quat[]
// is write-only plain cached stores published by kernel-end flush; cleanup
// writes identity for unreached + start nodes (disjoint bytes -> XCD-safe).
// ---------------------------------------------------------------------------
__global__ void __launch_bounds__(THREADS)
bfs_kernel(const float* __restrict__ eattr,
           const int* __restrict__ nbr,
           const int* __restrict__ eidx,
           ull* __restrict__ qrec,        // [N][4] packed queue records
           int* __restrict__ claim,
           unsigned* __restrict__ state,  // exchange slot per block (gen-tagged)
           int* __restrict__ ctrl,        // [1]=head, [2]=tail (solo burst)
           unsigned* __restrict__ slot,   // barrier slots, one per block
           float* __restrict__ out,       // [0]=start, [1..]=quat[N][4]
           const int* __restrict__ startp,
           int N) {
    const int tid = blockIdx.x * blockDim.x + threadIdx.x;
    const int T = BLOCKS * THREADS;
    float* quat = out + 1;
    const float4* eattr4 = (const float4*)eattr;
    const int start = *startp;
    unsigned phase = 0;

    __shared__ int s_wsum[THREADS / 64];
    __shared__ int s_wbase[THREADS / 64];
    __shared__ int s_carry;
    __shared__ int s_excl;
    __shared__ int s_total;

    // init: claim sentinel pairs (8B packed), start record. No quat init.
    for (int i = tid; i < (N >> 1); i += T) {
        int v0 = 2 * i, v1 = 2 * i + 1;
        unsigned lo = (v0 == start) ? 0xFFFFFFFFu : 0x7FFFFFFFu;
        unsigned hi = (v1 == start) ? 0xFFFFFFFFu : 0x7FFFFFFFu;
        st8(&((ull*)claim)[i], (ull)lo | ((ull)hi << 32));
    }
    if ((N & 1) && tid == 0)
        st_ag(&claim[N - 1], (N - 1 == start) ? -1 : 0x7FFFFFFF);
    if (tid == 0) {
        st8(&qrec[0], (ull)(unsigned)start | ((ull)0x3F800000u << 32)); // w=1.0
        st8(&qrec[1], 0ull);
        st8(&qrec[2], 0ull);
        out[0] = (float)start;   // plain: published by kernel-end flush
    }
    gsync(slot, phase);

    int head = 0, tail = 1;
    unsigned gen = 0;
    while (head < tail) {
        const int F = tail - head;

        if (F <= SOLO_MAX) {
            // ---- solo burst: block 0 chews levels alone (syncthreads only) ----
            if (blockIdx.x == 0) {
                int h = head, t = tail;
                while (h < t && (t - h) <= SOLO_MAX) {
                    const int Fb = t - h;
                    for (int e = threadIdx.x; e < Fb * DEG; e += THREADS) {
                        int p = h + (e >> 5), s = e & 31;
                        int u = (int)(unsigned)ld8(&qrec[4 * p]);
                        int v = nbr[(u << 5) + s];
                        int key = (p << 5) + s;
                        if (ld_ag(&claim[v]) > key) atomicMin(&claim[v], key);
                    }
                    __syncthreads();
                    int my_c = 0;
                    if ((int)threadIdx.x < Fb) {
                        int p = h + (int)threadIdx.x;
                        int u = (int)(unsigned)ld8(&qrec[4 * p]);
                        for (int s = 0; s < DEG; ++s)
                            if (ld_ag(&claim[nbr[(u << 5) + s]]) == ((p << 5) + s))
                                my_c++;
                    }
                    int incl = my_c;
                    for (int d = 1; d < 64; d <<= 1) {
                        int tt = __shfl_up(incl, d, 64);
                        if ((threadIdx.x & 63) >= (unsigned)d) incl += tt;
                    }
                    if (threadIdx.x == 63) s_total = incl;
                    __syncthreads();
                    int total = s_total;
                    if ((int)threadIdx.x < Fb) {
                        int p = h + (int)threadIdx.x;
                        ull r0 = ld8(&qrec[4 * p]);
                        ull r1 = ld8(&qrec[4 * p + 1]);
                        ull r2 = ld8(&qrec[4 * p + 2]);
                        int u = (int)(unsigned)r0;
                        float pw = __uint_as_float((unsigned)(r0 >> 32));
                        float px = __uint_as_float((unsigned)r1);
                        float py = __uint_as_float((unsigned)(r1 >> 32));
                        float pz = __uint_as_float((unsigned)r2);
                        int pos = t + (incl - my_c);
                        for (int s = 0; s < DEG; ++s) {
                            int v = nbr[(u << 5) + s];
                            if (ld_ag(&claim[v]) == ((p << 5) + s)) {
                                float4 q = eattr4[eidx[(u << 5) + s]];
                                float qw = q.x, qx = -q.y, qy = -q.z, qz = -q.w;
                                float nw = qw * pw - qx * px - qy * py - qz * pz;
                                float nx = qw * px + qx * pw + qy * pz - qz * py;
                                float ny = qw * py - qx * pz + qy * pw + qz * px;
                                float nz = qw * pz + qx * py - qy * px + qz * pw;
                                quat[4 * v + 0] = nw;  // plain cached
                                quat[4 * v + 1] = nx;
                                quat[4 * v + 2] = ny;
                                quat[4 * v + 3] = nz;
                                st8(&qrec[4 * pos],
                                    (ull)(unsigned)v | ((ull)__float_as_uint(nw) << 32));
                                st8(&qrec[4 * pos + 1],
                                    (ull)__float_as_uint(nx) | ((ull)__float_as_uint(ny) << 32));
                                st8(&qrec[4 * pos + 2], (ull)__float_as_uint(nz));
                                pos++;
                            }
                        }
                    }
                    __syncthreads();
                    h = t;
                    t += total;
                }
                if (threadIdx.x == 0) { st_ag(&ctrl[1], h); st_ag(&ctrl[2], t); }
            }
            gsync(slot, phase);
            head = ld_ag(&ctrl[1]);
            tail = ld_ag(&ctrl[2]);
        } else {
            // ---- grid level, 2 fence-free syncs ----
            // Region A: claims, x4 MLP, claim-filtered atomicMin
            {
                const int EDG = F * DEG;
                for (int e = tid; e < EDG; e += 4 * T) {
                    int ee[4]; bool ok[4]; int u[4], v[4], key[4], cl[4];
                    #pragma unroll
                    for (int k = 0; k < 4; ++k) {
                        ee[k] = e + k * T;
                        ok[k] = ee[k] < EDG;
                        int p = head + (ee[k] >> 5);
                        key[k] = (p << 5) + (ee[k] & 31);
                        u[k] = ok[k] ? (int)(unsigned)ld8(&qrec[4 * p]) : 0;
                    }
                    #pragma unroll
                    for (int k = 0; k < 4; ++k)
                        v[k] = ok[k] ? nbr[(u[k] << 5) + (ee[k] & 31)] : 0;
                    #pragma unroll
                    for (int k = 0; k < 4; ++k)
                        cl[k] = ok[k] ? ld_ag(&claim[v[k]]) : -1;
                    #pragma unroll
                    for (int k = 0; k < 4; ++k)
                        if (ok[k] && cl[k] > key[k]) atomicMin(&claim[v[k]], key[k]);
                }
            }
            gsync(slot, phase);

            // Region B: wins + block scan + exchange + append
            gen++;
            const int CH = (F + BLOCKS - 1) / BLOCKS;
            const int c0 = blockIdx.x * CH;
            const int c1 = min(F, c0 + CH);
            if (threadIdx.x == 0) s_carry = 0;
            __syncthreads();

            int ms[2] = {0, 0}, ofs[2] = {0, 0};
            #pragma unroll
            for (int st = 0; st < 2; ++st) {
                int i = c0 + st * THREADS + (int)threadIdx.x;
                int x = 0, mask = 0;
                if (i < c1) {
                    int p = head + i;
                    int u = (int)(unsigned)ld8(&qrec[4 * p]);
                    const int4* row = (const int4*)&nbr[u << 5];
                    int vv[32];
                    #pragma unroll
                    for (int r = 0; r < 8; ++r) {
                        int4 q4 = row[r];
                        vv[4 * r + 0] = q4.x; vv[4 * r + 1] = q4.y;
                        vv[4 * r + 2] = q4.z; vv[4 * r + 3] = q4.w;
                    }
                    int cl[32];
                    #pragma unroll
                    for (int s = 0; s < 32; ++s) cl[s] = ld_ag(&claim[vv[s]]);
                    #pragma unroll
                    for (int s = 0; s < 32; ++s)
                        if (cl[s] == ((p << 5) + s)) { mask |= 1 << s; x++; }
                }
                int lane = threadIdx.x & 63, wid = threadIdx.x >> 6;
                int incl = x;
                for (int d = 1; d < 64; d <<= 1) {
                    int tt = __shfl_up(incl, d, 64);
                    if (lane >= d) incl += tt;
                }
                if (lane == 63) s_wsum[wid] = incl;
                __syncthreads();
                if (threadIdx.x == 0) {
                    int acc = s_carry;
                    for (int w = 0; w < THREADS / 64; ++w) {
                        s_wbase[w] = acc;
                        acc += s_wsum[w];
                    }
                    s_carry = acc;
                }
                __syncthreads();
                ms[st] = mask;
                ofs[st] = s_wbase[wid] + incl - x;
                __syncthreads();
            }
            const int agg = s_carry;

            // wave-parallel all-to-all exchange, relaxed + generation tag
            if (threadIdx.x == 0)
                __hip_atomic_store(&state[blockIdx.x],
                                   ((gen & 0xFFu) << 24) | (unsigned)agg,
                                   __ATOMIC_RELAXED, __HIP_MEMORY_SCOPE_AGENT);
            if (threadIdx.x < 64) {
                unsigned sv;
                do {
                    sv = __hip_atomic_load(&state[threadIdx.x], __ATOMIC_RELAXED,
                                           __HIP_MEMORY_SCOPE_AGENT);
                } while ((sv >> 24) != (gen & 0xFFu));
                int a = (int)(sv & 0xFFFFFFu);
                int incl = a;
                for (int d = 1; d < 64; d <<= 1) {
                    int tt = __shfl_up(incl, d, 64);
                    if ((int)(threadIdx.x & 63) >= d) incl += tt;
                }
                int myincl = __shfl(incl, (int)blockIdx.x, 64);
                int mya = __shfl(a, (int)blockIdx.x, 64);
                int tot = __shfl(incl, 63, 64);
                if (threadIdx.x == 0) { s_excl = myincl - mya; s_total = tot; }
            }
            __syncthreads();
            const int excl = s_excl;
            const int total = s_total;

            // append: winners write quat (plain) + queue record (coherent)
            #pragma unroll
            for (int st = 0; st < 2; ++st) {
                int i = c0 + st * THREADS + (int)threadIdx.x;
                int mask = ms[st];
                if (i < c1 && mask) {
                    int p = head + i;
                    ull r0 = ld8(&qrec[4 * p]);
                    ull r1 = ld8(&qrec[4 * p + 1]);
                    ull r2 = ld8(&qrec[4 * p + 2]);
                    int u = (int)(unsigned)r0;
                    float pw = __uint_as_float((unsigned)(r0 >> 32));
                    float px = __uint_as_float((unsigned)r1);
                    float py = __uint_as_float((unsigned)(r1 >> 32));
                    float pz = __uint_as_float((unsigned)r2);
                    int pos = tail + excl + ofs[st];
                    while (mask) {
                        int s = __ffs(mask) - 1;
                        mask &= mask - 1;
                        int v = nbr[(u << 5) + s];
                        float4 q = eattr4[eidx[(u << 5) + s]];
                        float qw = q.x, qx = -q.y, qy = -q.z, qz = -q.w;
                        float nw = qw * pw - qx * px - qy * py - qz * pz;
                        float nx = qw * px + qx * pw + qy * pz - qz * py;
                        float ny = qw * py - qx * pz + qy * pw + qz * px;
                        float nz = qw * pz + qx * py - qy * px + qz * pw;
                        quat[4 * v + 0] = nw;  // plain cached, write-only
                        quat[4 * v + 1] = nx;
                        quat[4 * v + 2] = ny;
                        quat[4 * v + 3] = nz;
                        st8(&qrec[4 * pos],
                            (ull)(unsigned)v | ((ull)__float_as_uint(nw) << 32));
                        st8(&qrec[4 * pos + 1],
                            (ull)__float_as_uint(nx) | ((ull)__float_as_uint(ny) << 32));
                        st8(&qrec[4 * pos + 2], (ull)__float_as_uint(nz));
                        pos++;
                    }
                }
            }
            gsync(slot, phase);
            head = tail;
            tail += total;
        }
    }

    // cleanup: identity for unreached nodes and the start node (sole writers)
    for (int v = tid; v < N; v += T) {
        int c = ld_ag(&claim[v]);
        if (c == 0x7FFFFFFF || c == -1) {
            quat[4 * v + 0] = 1.0f;
            quat[4 * v + 1] = 0.0f;
            quat[4 * v + 2] = 0.0f;
            quat[4 * v + 3] = 0.0f;
        }
    }
}

extern "C" void kernel_launch(void* const* d_in, const int* in_sizes, int n_in,
                              void* d_out, int out_size, void* d_ws, size_t ws_size,
                              hipStream_t stream) {
    const float* eattr = (const float*)d_in[0];
    const int* edge_index = (const int*)d_in[1];
    const int* startp = (const int*)d_in[2];
    const int E = in_sizes[0] / 4;   // 640000
    const int N = E / DEG;           // 20000
    const int* dst = edge_index + E; // row 1 of [2, E]

    char* ws = (char*)d_ws;
    int* nbr = (int*)ws;            ws += (size_t)E * 4;
    int* eidx = (int*)ws;           ws += (size_t)E * 4;
    ull* qrec = (ull*)ws;           ws += (size_t)N * 32;
    int* claim = (int*)ws;          ws += (size_t)N * 4;
    unsigned int* state = (unsigned int*)ws; ws += (size_t)BLOCKS * 4;
    int* ctrl = (int*)ws;           ws += 64;
    unsigned int* slot = (unsigned int*)ws; ws += 256;

    sort_edges_kernel<<<dim3((E + 255) / 256), dim3(256), 0, stream>>>(
        eattr, dst, nbr, eidx, slot, E);

    float* out = (float*)d_out;
    bfs_kernel<<<dim3(BLOCKS), dim3(THREADS), 0, stream>>>(
        eattr, nbr, eidx, qrec, claim, state, ctrl, slot, out, startp, N);
}